// Round 15
// baseline (438.514 us; speedup 1.0000x reference)
//
#include <hip/hip_runtime.h>
#include <cstddef>
#include <cstdint>

#define NN 20000
#define EE 320000
#define ET (EE + NN)

typedef __attribute__((ext_vector_type(8))) short bf16x8;
typedef __attribute__((ext_vector_type(4))) float f32x4;

__device__ __forceinline__ unsigned short f2bf_rne(float f) {
  unsigned int u = __float_as_uint(f);
  u += 0x7FFF + ((u >> 16) & 1);
  return (unsigned short)(u >> 16);
}

__device__ __forceinline__ float bf2f(unsigned short b) {
  return __uint_as_float(((unsigned int)b) << 16);
}

__device__ __forceinline__ f32x4 up2(uint2 p) {
  f32x4 v = {__uint_as_float(p.x << 16), __uint_as_float(p.x & 0xFFFF0000u),
             __uint_as_float(p.y << 16), __uint_as_float(p.y & 0xFFFF0000u)};
  return v;
}

// ===================== fused prep: cvt + transposes + V16/Wstk + zero ============

__global__ __launch_bounds__(256) void prep_all(
    const float* __restrict__ x, unsigned short* __restrict__ xbf,
    const float* __restrict__ W0, unsigned short* __restrict__ W0T,
    const float* __restrict__ rW0, unsigned short* __restrict__ rW0T,
    const float* __restrict__ W1, unsigned short* __restrict__ W1T,
    const float* __restrict__ rW2, unsigned short* __restrict__ rW2T,
    const float* __restrict__ W2, const float* __restrict__ as2,
    const float* __restrict__ ad2, unsigned short* __restrict__ V16,
    unsigned short* __restrict__ WstkT, int* __restrict__ zbuf, int full) {
  int b = blockIdx.x, t = threadIdx.x;
  if (b < 5000) {
    int i = b * 256 + t;
    if (i < NN * 64) xbf[i] = f2bf_rne(x[i]);
    return;
  }
  b -= 5000;
  if (b < 64) {   // W0T: dst[n*64+k] = W0[k*256+n]
    int idx = b * 256 + t, n = idx >> 6, k = idx & 63;
    W0T[idx] = f2bf_rne(W0[(size_t)k * 256 + n]);
    return;
  }
  b -= 64;
  if (b < 64) {
    int idx = b * 256 + t, n = idx >> 6, k = idx & 63;
    rW0T[idx] = f2bf_rne(rW0[(size_t)k * 256 + n]);
    return;
  }
  b -= 64;
  if (b < 256) {  // W1T
    int idx = b * 256 + t, n = idx >> 8, k = idx & 255;
    W1T[idx] = f2bf_rne(W1[(size_t)k * 256 + n]);
    return;
  }
  b -= 256;
  if (b < 128) {  // rW2T
    int idx = b * 256 + t, n = idx >> 8, k = idx & 255;
    rW2T[idx] = f2bf_rne(rW2[(size_t)k * 128 + n]);
    return;
  }
  b -= 128;
  if (b < 157) {  // zero deg+cursor+hist+boff+bcur (2*NN+192 = 40192 ints)
    int i = b * 256 + t;
    if (i < 2 * NN + 192) zbuf[i] = 0;
    return;
  }
  b -= 157;
  if (!full) return;
  if (b < 16) {   // V16 row b
    int r = b, k = t, h = r & 7;
    const float* av = (r < 8) ? (as2 + h * 128) : (ad2 + h * 128);
    const float* wr = W2 + (size_t)k * 1024 + h * 128;
    float v = 0.f;
#pragma unroll 4
    for (int c = 0; c < 128; ++c) v += wr[c] * av[c];
    V16[(size_t)r * 256 + k] = f2bf_rne(v);
    return;
  }
  b -= 16;
  if (b < 128) {  // WstkT col-block b
    int c = b, k = t;
#pragma unroll
    for (int h = 0; h < 8; ++h)
      WstkT[(size_t)c * 2048 + h * 256 + k] =
          f2bf_rne(0.125f * W2[(size_t)k * 1024 + h * 128 + c]);
  }
}

#define PREP_BLOCKS (5000 + 64 + 64 + 256 + 128 + 157 + 16 + 128)

// ===================== small utility / fallback kernels =====================

__global__ __launch_bounds__(256) void zero_f32(float* __restrict__ p, int n) {
  int i = blockIdx.x * 256 + threadIdx.x;
  if (i < n) p[i] = 0.f;
}

__global__ void tconv(const float* __restrict__ src, unsigned short* __restrict__ dst,
                      int N) {
  int n = blockIdx.x, k = threadIdx.x, K = blockDim.x;
  dst[(size_t)n * K + k] = f2bf_rne(src[(size_t)k * N + n]);
}

// ===================== CSR build + degree-sorted permutation =====================

__global__ __launch_bounds__(256) void count_kernel(const int* __restrict__ ei,
                                                    int* __restrict__ deg) {
  int e = blockIdx.x * 256 + threadIdx.x;
  if (e < EE) {
    int d = ei[EE + e];
    if (d >= 0 && d < NN) atomicAdd(&deg[d], 1);
  }
}

// per-block inclusive scan of (deg+1) + block sums + degree histogram (desc keys)
__global__ __launch_bounds__(1024) void scan_blk(const int* __restrict__ deg,
    int* __restrict__ offs, int* __restrict__ bsum, int* __restrict__ hist) {
  __shared__ int s[1024];
  __shared__ int lh[64];
  int b = blockIdx.x, tid = threadIdx.x;
  if (tid < 64) lh[tid] = 0;
  int i = b * 1024 + tid;
  int d = (i < NN) ? (deg[i] + 1) : 0;   // +1 = self loop
  s[tid] = d;
  __syncthreads();
  if (i < NN) atomicAdd(&lh[63 - min(d, 63)], 1);
  for (int off = 1; off < 1024; off <<= 1) {
    int t = (tid >= off) ? s[tid - off] : 0;
    __syncthreads();
    s[tid] += t;
    __syncthreads();
  }
  if (i < NN) offs[i + 1] = s[tid];
  if (tid == 1023) bsum[b] = s[1023];
  if (tid < 64 && lh[tid]) atomicAdd(&hist[tid], lh[tid]);
}

__global__ void bucket_prefix(const int* __restrict__ hist, int* __restrict__ boff) {
  if (threadIdx.x == 0) {
    int run = 0;
    for (int k = 0; k < 64; ++k) { boff[k] = run; run += hist[k]; }
  }
}

__global__ __launch_bounds__(256) void scan_add(int* __restrict__ offs,
    const int* __restrict__ bsum) {
  int i = blockIdx.x * 256 + threadIdx.x;
  if (i == 0) offs[0] = 0;
  if (i < NN) {
    int b = i >> 10;
    int pre = 0;
    for (int k = 0; k < b; ++k) pre += bsum[k];
    offs[i + 1] += pre;
  }
}

__global__ __launch_bounds__(256) void perm_build(const int* __restrict__ offs,
    const int* __restrict__ boff, int* __restrict__ bcur, int* __restrict__ perm) {
  int n = blockIdx.x * 256 + threadIdx.x;
  if (n < NN) {
    int d = offs[n + 1] - offs[n];
    int key = 63 - min(d, 63);
    int pos = atomicAdd(&bcur[key], 1);
    perm[boff[key] + pos] = n;
  }
}

__global__ __launch_bounds__(256) void scatter_kernel(const int* __restrict__ ei,
    const int* __restrict__ offs, int* __restrict__ cursor, int* __restrict__ csr) {
  int e = blockIdx.x * 256 + threadIdx.x;
  if (e >= ET) return;
  int s, d;
  if (e < EE) { s = ei[e]; d = ei[EE + e]; }
  else        { s = e - EE; d = s; }
  if (s < 0 || s >= NN || d < 0 || d >= NN) return;
  int pos = atomicAdd(&cursor[d], 1);
  csr[offs[d] + pos] = s;
}

// ===================== bf16 MFMA GEMM: C[M,N] = A[M,K] @ BT^T (+bias) =============

__global__ __launch_bounds__(256) void gemm_mfma(const unsigned short* __restrict__ A,
    const unsigned short* __restrict__ BT, const float* __restrict__ bias,
    float* __restrict__ C, int M, int K, int ldc) {
  int bm = blockIdx.y * 64, bn = blockIdx.x * 64;
  int tid = threadIdx.x;
  int w = tid >> 6, l = tid & 63;
  int wm = bm + w * 16;
  if (wm >= M) return;
  int lane16 = l & 15, q = l >> 4;
  const unsigned short* ap = A + (size_t)(wm + lane16) * K + q * 8;
  const unsigned short* bp = BT + (size_t)(bn + lane16) * K + q * 8;
  f32x4 acc0 = {0.f, 0.f, 0.f, 0.f}, acc1 = acc0, acc2 = acc0, acc3 = acc0;
#pragma unroll 2
  for (int k0 = 0; k0 < K; k0 += 32) {
    bf16x8 a  = *(const bf16x8*)(ap + k0);
    bf16x8 b0 = *(const bf16x8*)(bp + k0);
    bf16x8 b1 = *(const bf16x8*)(bp + (size_t)16 * K + k0);
    bf16x8 b2 = *(const bf16x8*)(bp + (size_t)32 * K + k0);
    bf16x8 b3 = *(const bf16x8*)(bp + (size_t)48 * K + k0);
    acc0 = __builtin_amdgcn_mfma_f32_16x16x32_bf16(a, b0, acc0, 0, 0, 0);
    acc1 = __builtin_amdgcn_mfma_f32_16x16x32_bf16(a, b1, acc1, 0, 0, 0);
    acc2 = __builtin_amdgcn_mfma_f32_16x16x32_bf16(a, b2, acc2, 0, 0, 0);
    acc3 = __builtin_amdgcn_mfma_f32_16x16x32_bf16(a, b3, acc3, 0, 0, 0);
  }
  int row0 = wm + q * 4;
  int c0 = bn + lane16;
  float bi0 = bias ? bias[c0]      : 0.f;
  float bi1 = bias ? bias[c0 + 16] : 0.f;
  float bi2 = bias ? bias[c0 + 32] : 0.f;
  float bi3 = bias ? bias[c0 + 48] : 0.f;
#pragma unroll
  for (int r = 0; r < 4; ++r) {
    float* crow = C + (size_t)(row0 + r) * ldc;
    crow[c0]      = acc0[r] + bi0;
    crow[c0 + 16] = acc1[r] + bi1;
    crow[c0 + 32] = acc2[r] + bi2;
    crow[c0 + 48] = acc3[r] + bi3;
  }
}

// fused layer-0 GEMMs: z=0 -> h(bf16)+logits; z=1 -> residual bf16+bias.  K=64.
__global__ __launch_bounds__(256) void gemm_l0(const unsigned short* __restrict__ A,
    const unsigned short* __restrict__ W0T, const unsigned short* __restrict__ rW0T,
    const float* __restrict__ rb0, unsigned short* __restrict__ hG,
    unsigned short* __restrict__ resout, const float* __restrict__ as_w,
    const float* __restrict__ ad_w, float* __restrict__ als,
    float* __restrict__ ald, int M) {
  int z = blockIdx.z;
  int bm = blockIdx.y * 64, bn = blockIdx.x * 64;
  int tid = threadIdx.x;
  int w = tid >> 6, l = tid & 63;
  int wm = bm + w * 16;
  if (wm >= M) return;
  int lane16 = l & 15, q = l >> 4;
  const unsigned short* BT = z ? rW0T : W0T;
  const unsigned short* ap = A + (size_t)(wm + lane16) * 64 + q * 8;
  const unsigned short* bp = BT + (size_t)(bn + lane16) * 64 + q * 8;
  f32x4 acc0 = {0.f, 0.f, 0.f, 0.f}, acc1 = acc0, acc2 = acc0, acc3 = acc0;
#pragma unroll
  for (int k0 = 0; k0 < 64; k0 += 32) {
    bf16x8 a  = *(const bf16x8*)(ap + k0);
    bf16x8 b0 = *(const bf16x8*)(bp + k0);
    bf16x8 b1 = *(const bf16x8*)(bp + (size_t)16 * 64 + k0);
    bf16x8 b2 = *(const bf16x8*)(bp + (size_t)32 * 64 + k0);
    bf16x8 b3 = *(const bf16x8*)(bp + (size_t)48 * 64 + k0);
    acc0 = __builtin_amdgcn_mfma_f32_16x16x32_bf16(a, b0, acc0, 0, 0, 0);
    acc1 = __builtin_amdgcn_mfma_f32_16x16x32_bf16(a, b1, acc1, 0, 0, 0);
    acc2 = __builtin_amdgcn_mfma_f32_16x16x32_bf16(a, b2, acc2, 0, 0, 0);
    acc3 = __builtin_amdgcn_mfma_f32_16x16x32_bf16(a, b3, acc3, 0, 0, 0);
  }
  int row0 = wm + q * 4;
  int c0 = bn + lane16;
  if (z == 1) {
    float bi0 = rb0[c0], bi1 = rb0[c0 + 16], bi2 = rb0[c0 + 32], bi3 = rb0[c0 + 48];
#pragma unroll
    for (int r = 0; r < 4; ++r) {
      unsigned short* crow = resout + (size_t)(row0 + r) * 256;
      crow[c0]      = f2bf_rne(acc0[r] + bi0);
      crow[c0 + 16] = f2bf_rne(acc1[r] + bi1);
      crow[c0 + 32] = f2bf_rne(acc2[r] + bi2);
      crow[c0 + 48] = f2bf_rne(acc3[r] + bi3);
    }
    return;
  }
#pragma unroll
  for (int r = 0; r < 4; ++r) {
    unsigned short* crow = hG + (size_t)(row0 + r) * 256;
    crow[c0]      = f2bf_rne(acc0[r]);
    crow[c0 + 16] = f2bf_rne(acc1[r]);
    crow[c0 + 32] = f2bf_rne(acc2[r]);
    crow[c0 + 48] = f2bf_rne(acc3[r]);
  }
  float asA0 = as_w[c0],      asA1 = as_w[c0 + 16];
  float adA0 = ad_w[c0],      adA1 = ad_w[c0 + 16];
  float asB0 = as_w[c0 + 32], asB1 = as_w[c0 + 48];
  float adB0 = ad_w[c0 + 32], adB1 = ad_w[c0 + 48];
  int hA = (bn >> 5), hB = hA + 1;
#pragma unroll
  for (int r = 0; r < 4; ++r) {
    float sA = acc0[r] * asA0 + acc1[r] * asA1;
    float dA = acc0[r] * adA0 + acc1[r] * adA1;
    float sB = acc2[r] * asB0 + acc3[r] * asB1;
    float dB = acc2[r] * adB0 + acc3[r] * adB1;
#pragma unroll
    for (int off = 8; off >= 1; off >>= 1) {
      sA += __shfl_xor(sA, off);
      dA += __shfl_xor(dA, off);
      sB += __shfl_xor(sB, off);
      dB += __shfl_xor(dB, off);
    }
    if (lane16 == 0) {
      int row = row0 + r;
      als[row * 8 + hA] = sA;
      ald[row * 8 + hA] = dA;
      als[row * 8 + hB] = sB;
      ald[row * 8 + hB] = dB;
    }
  }
}

// bf16-out h GEMM with FUSED attention logits (layer 1, K=256)
__global__ __launch_bounds__(256) void gemm_mfma_bf_al(const unsigned short* __restrict__ A,
    const unsigned short* __restrict__ BT, unsigned short* __restrict__ C,
    const float* __restrict__ as_w, const float* __restrict__ ad_w,
    float* __restrict__ als, float* __restrict__ ald, int M, int K) {
  int bm = blockIdx.y * 64, bn = blockIdx.x * 64;
  int tid = threadIdx.x;
  int w = tid >> 6, l = tid & 63;
  int wm = bm + w * 16;
  if (wm >= M) return;
  int lane16 = l & 15, q = l >> 4;
  const unsigned short* ap = A + (size_t)(wm + lane16) * K + q * 8;
  const unsigned short* bp = BT + (size_t)(bn + lane16) * K + q * 8;
  f32x4 acc0 = {0.f, 0.f, 0.f, 0.f}, acc1 = acc0, acc2 = acc0, acc3 = acc0;
#pragma unroll 2
  for (int k0 = 0; k0 < K; k0 += 32) {
    bf16x8 a  = *(const bf16x8*)(ap + k0);
    bf16x8 b0 = *(const bf16x8*)(bp + k0);
    bf16x8 b1 = *(const bf16x8*)(bp + (size_t)16 * K + k0);
    bf16x8 b2 = *(const bf16x8*)(bp + (size_t)32 * K + k0);
    bf16x8 b3 = *(const bf16x8*)(bp + (size_t)48 * K + k0);
    acc0 = __builtin_amdgcn_mfma_f32_16x16x32_bf16(a, b0, acc0, 0, 0, 0);
    acc1 = __builtin_amdgcn_mfma_f32_16x16x32_bf16(a, b1, acc1, 0, 0, 0);
    acc2 = __builtin_amdgcn_mfma_f32_16x16x32_bf16(a, b2, acc2, 0, 0, 0);
    acc3 = __builtin_amdgcn_mfma_f32_16x16x32_bf16(a, b3, acc3, 0, 0, 0);
  }
  int row0 = wm + q * 4;
  int c0 = bn + lane16;
#pragma unroll
  for (int r = 0; r < 4; ++r) {
    unsigned short* crow = C + (size_t)(row0 + r) * 256;
    crow[c0]      = f2bf_rne(acc0[r]);
    crow[c0 + 16] = f2bf_rne(acc1[r]);
    crow[c0 + 32] = f2bf_rne(acc2[r]);
    crow[c0 + 48] = f2bf_rne(acc3[r]);
  }
  float asA0 = as_w[c0],      asA1 = as_w[c0 + 16];
  float adA0 = ad_w[c0],      adA1 = ad_w[c0 + 16];
  float asB0 = as_w[c0 + 32], asB1 = as_w[c0 + 48];
  float adB0 = ad_w[c0 + 32], adB1 = ad_w[c0 + 48];
  int hA = (bn >> 5), hB = hA + 1;
#pragma unroll
  for (int r = 0; r < 4; ++r) {
    float sA = acc0[r] * asA0 + acc1[r] * asA1;
    float dA = acc0[r] * adA0 + acc1[r] * adA1;
    float sB = acc2[r] * asB0 + acc3[r] * asB1;
    float dB = acc2[r] * adB0 + acc3[r] * adB1;
#pragma unroll
    for (int off = 8; off >= 1; off >>= 1) {
      sA += __shfl_xor(sA, off);
      dA += __shfl_xor(dA, off);
      sB += __shfl_xor(sB, off);
      dB += __shfl_xor(dB, off);
    }
    if (lane16 == 0) {
      int row = row0 + r;
      als[row * 8 + hA] = sA;
      ald[row * 8 + hA] = dA;
      als[row * 8 + hB] = sB;
      ald[row * 8 + hB] = dB;
    }
  }
}

// fused layer-2 small GEMMs: x=0 -> al16 logits; x=1,2 -> res2 (N=128, fp32+bias)
__global__ __launch_bounds__(256) void gemm_l2a(const unsigned short* __restrict__ A,
    const unsigned short* __restrict__ V16, const unsigned short* __restrict__ rW2T,
    const float* __restrict__ rb2, float* __restrict__ als, float* __restrict__ ald,
    float* __restrict__ res2, int M) {
  int bx = blockIdx.x;
  int bm = blockIdx.y * 64;
  int tid = threadIdx.x;
  int w = tid >> 6, l = tid & 63;
  int wm = bm + w * 16;
  if (wm >= M) return;
  int lane16 = l & 15, q = l >> 4;
  const unsigned short* ap = A + (size_t)(wm + lane16) * 256 + q * 8;
  if (bx == 0) {
    const unsigned short* bp = V16 + (size_t)lane16 * 256 + q * 8;
    f32x4 acc = {0.f, 0.f, 0.f, 0.f};
#pragma unroll
    for (int k0 = 0; k0 < 256; k0 += 32) {
      bf16x8 a = *(const bf16x8*)(ap + k0);
      bf16x8 b = *(const bf16x8*)(bp + k0);
      acc = __builtin_amdgcn_mfma_f32_16x16x32_bf16(a, b, acc, 0, 0, 0);
    }
    int row0 = wm + q * 4;
    float* dst = (lane16 < 8) ? als : ald;
    int h = lane16 & 7;
#pragma unroll
    for (int r = 0; r < 4; ++r)
      dst[(size_t)(row0 + r) * 8 + h] = acc[r];
    return;
  }
  int bn = (bx - 1) * 64;
  const unsigned short* bp = rW2T + (size_t)(bn + lane16) * 256 + q * 8;
  f32x4 acc0 = {0.f, 0.f, 0.f, 0.f}, acc1 = acc0, acc2 = acc0, acc3 = acc0;
#pragma unroll 2
  for (int k0 = 0; k0 < 256; k0 += 32) {
    bf16x8 a  = *(const bf16x8*)(ap + k0);
    bf16x8 b0 = *(const bf16x8*)(bp + k0);
    bf16x8 b1 = *(const bf16x8*)(bp + (size_t)16 * 256 + k0);
    bf16x8 b2 = *(const bf16x8*)(bp + (size_t)32 * 256 + k0);
    bf16x8 b3 = *(const bf16x8*)(bp + (size_t)48 * 256 + k0);
    acc0 = __builtin_amdgcn_mfma_f32_16x16x32_bf16(a, b0, acc0, 0, 0, 0);
    acc1 = __builtin_amdgcn_mfma_f32_16x16x32_bf16(a, b1, acc1, 0, 0, 0);
    acc2 = __builtin_amdgcn_mfma_f32_16x16x32_bf16(a, b2, acc2, 0, 0, 0);
    acc3 = __builtin_amdgcn_mfma_f32_16x16x32_bf16(a, b3, acc3, 0, 0, 0);
  }
  int row0 = wm + q * 4;
  int c0 = bn + lane16;
  float bi0 = rb2[c0], bi1 = rb2[c0 + 16], bi2 = rb2[c0 + 32], bi3 = rb2[c0 + 48];
#pragma unroll
  for (int r = 0; r < 4; ++r) {
    float* crow = res2 + (size_t)(row0 + r) * 128;
    crow[c0]      = acc0[r] + bi0;
    crow[c0 + 16] = acc1[r] + bi1;
    crow[c0 + 32] = acc2[r] + bi2;
    crow[c0 + 48] = acc3[r] + bi3;
  }
}

// standalone al16 (used when res2 buffer is absent)
__global__ __launch_bounds__(256) void gemm_al16(const unsigned short* __restrict__ A,
    const unsigned short* __restrict__ V16, float* __restrict__ als,
    float* __restrict__ ald, int M) {
  int bm = blockIdx.x * 64;
  int tid = threadIdx.x;
  int w = tid >> 6, l = tid & 63;
  int wm = bm + w * 16;
  if (wm >= M) return;
  int lane16 = l & 15, q = l >> 4;
  const unsigned short* ap = A + (size_t)(wm + lane16) * 256 + q * 8;
  const unsigned short* bp = V16 + (size_t)lane16 * 256 + q * 8;
  f32x4 acc = {0.f, 0.f, 0.f, 0.f};
#pragma unroll
  for (int k0 = 0; k0 < 256; k0 += 32) {
    bf16x8 a = *(const bf16x8*)(ap + k0);
    bf16x8 b = *(const bf16x8*)(bp + k0);
    acc = __builtin_amdgcn_mfma_f32_16x16x32_bf16(a, b, acc, 0, 0, 0);
  }
  int row0 = wm + q * 4;
  float* dst = (lane16 < 8) ? als : ald;
  int h = lane16 & 7;
#pragma unroll
  for (int r = 0; r < 4; ++r)
    dst[(size_t)(row0 + r) * 8 + h] = acc[r];
}

// ===================== LDS-tiled split-K Y GEMM ==================================

__global__ __launch_bounds__(256) void gemm_y_tiled(const unsigned short* __restrict__ A,
    const unsigned short* __restrict__ BT, float* __restrict__ P, int M) {
  __shared__ unsigned short sA[64][72];
  __shared__ unsigned short sB[128][72];
  int bm = blockIdx.x * 64, s = blockIdx.y;
  int tid = threadIdx.x;
  int w = tid >> 6, l = tid & 63;
  int lane16 = l & 15, q = l >> 4;
  int soff = s * 512;
  int r = tid >> 3, c = (tid & 7) * 8;
  int rA0 = min(bm + r, M - 1);
  int rA1 = min(bm + r + 32, M - 1);
  f32x4 acc[8] = {};
#pragma unroll 1
  for (int kt = 0; kt < 8; ++kt) {
    int kb = soff + kt * 64 + c;
    *(bf16x8*)&sA[r][c]      = *(const bf16x8*)(A + (size_t)rA0 * 2048 + kb);
    *(bf16x8*)&sA[r + 32][c] = *(const bf16x8*)(A + (size_t)rA1 * 2048 + kb);
#pragma unroll
    for (int rr = 0; rr < 4; ++rr)
      *(bf16x8*)&sB[r + rr * 32][c] = *(const bf16x8*)(BT + (size_t)(r + rr * 32) * 2048 + kb);
    __syncthreads();
#pragma unroll
    for (int kk = 0; kk < 2; ++kk) {
      bf16x8 a = *(const bf16x8*)&sA[w * 16 + lane16][kk * 32 + q * 8];
#pragma unroll
      for (int t = 0; t < 8; ++t) {
        bf16x8 b = *(const bf16x8*)&sB[t * 16 + lane16][kk * 32 + q * 8];
        acc[t] = __builtin_amdgcn_mfma_f32_16x16x32_bf16(a, b, acc[t], 0, 0, 0);
      }
    }
    __syncthreads();
  }
  int row0 = bm + w * 16 + q * 4;
  float* pbase = P + (size_t)s * ((size_t)M * 128);
#pragma unroll
  for (int r2 = 0; r2 < 4; ++r2) {
    if (row0 + r2 < M) {
      float* prow = pbase + (size_t)(row0 + r2) * 128 + lane16;
#pragma unroll
      for (int t = 0; t < 8; ++t) prow[t * 16] = acc[t][r2];
    }
  }
}

// ===================== attention logits (fallback path only) =====================

__global__ __launch_bounds__(256) void al2(const float* __restrict__ h,
    const float* __restrict__ aw_s, const float* __restrict__ aw_d,
    float* __restrict__ als, float* __restrict__ ald) {
  int n = blockIdx.x, tid = threadIdx.x;
  int j = tid & 127;
  __shared__ float ss[256], sd[256];
  float v = h[(size_t)n * 256 + tid];
  ss[tid] = v * aw_s[tid];
  sd[tid] = v * aw_d[tid];
  __syncthreads();
  for (int off = 64; off > 0; off >>= 1) {
    if (j < off) { ss[tid] += ss[tid + off]; sd[tid] += sd[tid + off]; }
    __syncthreads();
  }
  if (j == 0) {
    int hh = tid >> 7;
    als[n * 2 + hh] = ss[tid];
    ald[n * 2 + hh] = sd[tid];
  }
}

// ===================== wave-per-node agg + LN + residual + ELU, layers 0/1 ========
// Degree-sorted node assignment via perm.

__global__ __launch_bounds__(256) void agg_epi_w(const unsigned short* __restrict__ hG,
    const float* __restrict__ als, const float* __restrict__ ald,
    const int* __restrict__ offs, const int* __restrict__ csr,
    const int* __restrict__ perm,
    const float* __restrict__ bias, const float* __restrict__ lng,
    const float* __restrict__ lnb, const unsigned short* __restrict__ resb,
    const float* __restrict__ rw, unsigned short* __restrict__ outbf) {
  int w = threadIdx.x >> 6, l = threadIdx.x & 63;
  int idx = blockIdx.x * 4 + w;
  if (idx >= NN) return;
  int n = perm[idx];
  int r0 = offs[n], r1 = offs[n + 1], deg = r1 - r0;
  int h8 = l & 7, e8 = l >> 3, hl = l >> 3;
  float aldn = ald[n * 8 + h8];
  f32x4 acc = {0.f, 0.f, 0.f, 0.f};
  float denacc = 0.f;
  for (int c0 = 0; c0 < deg; c0 += 8) {
    int cn = min(8, deg - c0);
    int src_my = csr[r0 + c0 + min(e8, cn - 1)];
    float ev = als[src_my * 8 + h8] + aldn;
    ev = ev >= 0.f ? ev : 0.2f * ev;
    float aexp = (e8 < cn) ? __expf(ev) : 0.f;
    denacc += aexp;
#pragma unroll 2
    for (int e = 0; e < cn; ++e) {
      int s = __shfl(src_my, e * 8);
      float a = __shfl(aexp, e * 8 + hl);
      uint2 p = *(const uint2*)(hG + (size_t)s * 256 + l * 4);
      acc += a * up2(p);
    }
  }
  denacc += __shfl_xor(denacc, 8);
  denacc += __shfl_xor(denacc, 16);
  denacc += __shfl_xor(denacc, 32);
  float den = __shfl(denacc, hl);
  float dinv = 1.f / (den + 1e-16f);
  float4 bi = ((const float4*)bias)[l];
  uint2 pb = ((const uint2*)resb)[(size_t)n * 64 + l];
  f32x4 rr = up2(pb);
  f32x4 val = {acc.x * dinv + bi.x, acc.y * dinv + bi.y,
               acc.z * dinv + bi.z, acc.w * dinv + bi.w};
  float v1 = val.x + val.y + val.z + val.w;
  float v2 = val.x * val.x + val.y * val.y + val.z * val.z + val.w * val.w;
#pragma unroll
  for (int off = 32; off >= 1; off >>= 1) {
    v1 += __shfl_xor(v1, off);
    v2 += __shfl_xor(v2, off);
  }
  float mu = v1 * (1.f / 256.f);
  float var = v2 * (1.f / 256.f) - mu * mu;
  float rs = rsqrtf(var + 1e-5f);
  float sig = 1.f / (1.f + __expf(-rw[0]));
  float4 lg = ((const float4*)lng)[l];
  float4 lb = ((const float4*)lnb)[l];
  float ov[4];
  const float* valp = (const float*)&val;
  const float* rrp = (const float*)&rr;
  const float* lgp = &lg.x;
  const float* lbp = &lb.x;
#pragma unroll
  for (int k = 0; k < 4; ++k) {
    float rv = (valp[k] - mu) * rs * lgp[k] + lbp[k] + sig * rrp[k];
    ov[k] = rv > 0.f ? rv : (__expf(rv) - 1.f);
  }
  uint2 pk;
  pk.x = (unsigned)f2bf_rne(ov[0]) | ((unsigned)f2bf_rne(ov[1]) << 16);
  pk.y = (unsigned)f2bf_rne(ov[2]) | ((unsigned)f2bf_rne(ov[3]) << 16);
  ((uint2*)outbf)[(size_t)n * 64 + l] = pk;
}

// ===================== wave-per-node layer-2 aggregation ==========================

__global__ __launch_bounds__(256) void agg_y_w(const unsigned short* __restrict__ hbf,
    const float* __restrict__ als, const float* __restrict__ ald,
    const int* __restrict__ offs, const int* __restrict__ csr,
    const int* __restrict__ perm, unsigned short* __restrict__ Y) {
  int w = threadIdx.x >> 6, l = threadIdx.x & 63;
  int idx = blockIdx.x * 4 + w;
  if (idx >= NN) return;
  int n = perm[idx];
  int r0 = offs[n], r1 = offs[n + 1], deg = r1 - r0;
  int h8 = l & 7, e8 = l >> 3;
  float aldn = ald[n * 8 + h8];
  f32x4 accv[8] = {};
  float denacc = 0.f;
  for (int c0 = 0; c0 < deg; c0 += 8) {
    int cn = min(8, deg - c0);
    int src_my = csr[r0 + c0 + min(e8, cn - 1)];
    float ev = als[src_my * 8 + h8] + aldn;
    ev = ev >= 0.f ? ev : 0.2f * ev;
    float aexp = (e8 < cn) ? __expf(ev) : 0.f;
    denacc += aexp;
    for (int e = 0; e < cn; ++e) {
      int s = __shfl(src_my, e * 8);
      uint2 p = *(const uint2*)(hbf + (size_t)s * 256 + l * 4);
      f32x4 v = up2(p);
#pragma unroll
      for (int h = 0; h < 8; ++h) {
        float a = __shfl(aexp, e * 8 + h);
        accv[h] += a * v;
      }
    }
  }
  denacc += __shfl_xor(denacc, 8);
  denacc += __shfl_xor(denacc, 16);
  denacc += __shfl_xor(denacc, 32);
  unsigned short* yrow = Y + (size_t)n * 2048;
#pragma unroll
  for (int h = 0; h < 8; ++h) {
    float dh = __shfl(denacc, h);
    float sc = 1.f / (dh + 1e-16f);
    f32x4 t = accv[h];
    uint2 pk;
    pk.x = (unsigned)f2bf_rne(t.x * sc) | ((unsigned)f2bf_rne(t.y * sc) << 16);
    pk.y = (unsigned)f2bf_rne(t.z * sc) | ((unsigned)f2bf_rne(t.w * sc) << 16);
    *(uint2*)(yrow + h * 256 + l * 4) = pk;
  }
}

// ===================== fallback layer-2 pair aggregation (round-4 path) ===========

__global__ __launch_bounds__(256) void agg2_pair(const float* __restrict__ h2,
    const float* __restrict__ als, const float* __restrict__ ald,
    const int* __restrict__ offs, const int* __restrict__ csr,
    float* __restrict__ acc_out) {
  int n = blockIdx.x, tid = threadIdx.x;
  int r0 = offs[n], r1 = offs[n + 1];
  __shared__ float s_red[256];
  __shared__ float s_dn[2];
  int hh = tid >> 7, j = tid & 127;
  float aldn = ald[n * 2 + hh];
  float sm = 0.f;
  for (int i = r0 + j; i < r1; i += 128) {
    int s = csr[i];
    float ev = als[s * 2 + hh] + aldn;
    ev = ev >= 0.f ? ev : 0.2f * ev;
    sm += __expf(ev);
  }
  s_red[tid] = sm;
  __syncthreads();
  for (int off = 64; off > 0; off >>= 1) {
    if (j < off) s_red[tid] += s_red[tid + off];
    __syncthreads();
  }
  if (j == 0) s_dn[hh] = s_red[tid] + 1e-16f;
  __syncthreads();
  float dinv = 1.f / s_dn[hh];
  float acc = 0.f;
  for (int i = r0; i < r1; ++i) {
    int s = csr[i];
    float ev = als[s * 2 + hh] + aldn;
    ev = ev >= 0.f ? ev : 0.2f * ev;
    float alpha = __expf(ev) * dinv;
    acc += alpha * h2[(size_t)s * 256 + tid];
  }
  s_red[tid] = acc;
  __syncthreads();
  if (tid < 128)
    acc_out[(size_t)n * 128 + tid] += 0.125f * (s_red[tid] + s_red[tid + 128]);
}

// ===================== layer-2 epilogues ====================

__global__ __launch_bounds__(128) void epi_out_res4(const float* __restrict__ P,
    const float* __restrict__ b2, const float* __restrict__ lng,
    const float* __restrict__ lnb, const float* __restrict__ res2,
    const float* __restrict__ rw, float* __restrict__ out) {
  int n = blockIdx.x, tid = threadIdx.x;
  __shared__ float sw1[2], sw2[2];
  size_t stride = (size_t)NN * 128;
  size_t idx = (size_t)n * 128 + tid;
  float g = P[idx] + P[stride + idx] + P[2 * stride + idx] + P[3 * stride + idx] + b2[tid];
  float v1 = g, v2 = g * g;
#pragma unroll
  for (int off = 32; off >= 1; off >>= 1) {
    v1 += __shfl_xor(v1, off);
    v2 += __shfl_xor(v2, off);
  }
  if ((tid & 63) == 0) { sw1[tid >> 6] = v1; sw2[tid >> 6] = v2; }
  __syncthreads();
  float tot1 = sw1[0] + sw1[1], tot2 = sw2[0] + sw2[1];
  float mu = tot1 * (1.f / 128.f);
  float var = tot2 * (1.f / 128.f) - mu * mu;
  float rs = rsqrtf(var + 1e-5f);
  float sig = 1.f / (1.f + __expf(-rw[0]));
  out[idx] = (g - mu) * rs * lng[tid] + lnb[tid] + sig * res2[idx];
}

__global__ __launch_bounds__(128) void epi_out_res(float* __restrict__ acc,
    const float* __restrict__ b2, const float* __restrict__ lng,
    const float* __restrict__ lnb, const float* __restrict__ res2,
    const float* __restrict__ rw) {
  int n = blockIdx.x, tid = threadIdx.x;
  __shared__ float s1[128], s2[128];
  __shared__ float s_mu, s_rs;
  float g = acc[(size_t)n * 128 + tid] + b2[tid];
  s1[tid] = g; s2[tid] = g * g;
  __syncthreads();
  for (int off = 64; off > 0; off >>= 1) {
    if (tid < off) { s1[tid] += s1[tid + off]; s2[tid] += s2[tid + off]; }
    __syncthreads();
  }
  if (tid == 0) {
    float mu = s1[0] * (1.f / 128.f);
    float var = s2[0] * (1.f / 128.f) - mu * mu;
    s_mu = mu; s_rs = rsqrtf(var + 1e-5f);
  }
  __syncthreads();
  float sig = 1.f / (1.f + __expf(-rw[0]));
  float lnv = (g - s_mu) * s_rs * lng[tid] + lnb[tid];
  acc[(size_t)n * 128 + tid] = lnv + sig * res2[(size_t)n * 128 + tid];
}

__global__ __launch_bounds__(128) void epi_out_mv(float* __restrict__ acc,
    const float* __restrict__ b2, const float* __restrict__ lng,
    const float* __restrict__ lnb, const unsigned short* __restrict__ hB,
    const float* __restrict__ rW2, const float* __restrict__ rb2,
    const float* __restrict__ rw) {
  int n = blockIdx.x, tid = threadIdx.x;
  __shared__ float srow[256];
  __shared__ float s1[128], s2[128];
  __shared__ float s_mu, s_rs;
  srow[tid] = bf2f(hB[(size_t)n * 256 + tid]);
  srow[tid + 128] = bf2f(hB[(size_t)n * 256 + tid + 128]);
  float g = acc[(size_t)n * 128 + tid] + b2[tid];
  s1[tid] = g; s2[tid] = g * g;
  __syncthreads();
  for (int off = 64; off > 0; off >>= 1) {
    if (tid < off) { s1[tid] += s1[tid + off]; s2[tid] += s2[tid + off]; }
    __syncthreads();
  }
  if (tid == 0) {
    float mu = s1[0] * (1.f / 128.f);
    float var = s2[0] * (1.f / 128.f) - mu * mu;
    s_mu = mu; s_rs = rsqrtf(var + 1e-5f);
  }
  __syncthreads();
  float rv = rb2[tid];
#pragma unroll 4
  for (int k = 0; k < 256; ++k) rv += srow[k] * rW2[(size_t)k * 128 + tid];
  float sig = 1.f / (1.f + __expf(-rw[0]));
  float lnv = (g - s_mu) * s_rs * lng[tid] + lnb[tid];
  acc[(size_t)n * 128 + tid] = lnv + sig * rv;
}

// ===================== launch ====================================================

extern "C" void kernel_launch(void* const* d_in, const int* in_sizes, int n_in,
                              void* d_out, int out_size, void* d_ws, size_t ws_size,
                              hipStream_t stream) {
  const float* x   = (const float*)d_in[0];
  const int*   ei  = (const int*)d_in[1];   // int64 in reference -> int32 on device
  const float* W0  = (const float*)d_in[2];
  const float* b0  = (const float*)d_in[3];
  const float* as0 = (const float*)d_in[4];
  const float* ad0 = (const float*)d_in[5];
  const float* lng0= (const float*)d_in[6];
  const float* lnb0= (const float*)d_in[7];
  const float* rW0 = (const float*)d_in[8];
  const float* rb0 = (const float*)d_in[9];
  const float* rw0 = (const float*)d_in[10];
  const float* W1  = (const float*)d_in[11];
  const float* b1  = (const float*)d_in[12];
  const float* as1 = (const float*)d_in[13];
  const float* ad1 = (const float*)d_in[14];
  const float* lng1= (const float*)d_in[15];
  const float* lnb1= (const float*)d_in[16];
  const float* rw1 = (const float*)d_in[17];
  const float* W2  = (const float*)d_in[18];
  const float* b2  = (const float*)d_in[19];
  const float* as2 = (const float*)d_in[20];
  const float* ad2 = (const float*)d_in[21];
  const float* lng2= (const float*)d_in[22];
  const float* lnb2= (const float*)d_in[23];
  const float* rW2 = (const float*)d_in[24];
  const float* rb2 = (const float*)d_in[25];
  const float* rw2 = (const float*)d_in[26];
  float* outp = (float*)d_out;

  char* w = (char*)d_ws;
  auto carve = [&](size_t bytes) -> char* {
    char* p = w;
    w += (bytes + 255) & ~(size_t)255;
    return p;
  };
  // bufH+bufR contiguous; dead during layer 2 (res2 path) -> 40.96 MB split-K partials
  float* bufH = (float*)carve((size_t)NN * 256 * 4);
  float* bufR = (float*)carve((size_t)NN * 256 * 4);
  float* als  = (float*)carve((size_t)NN * 8 * 4);
  float* ald  = (float*)carve((size_t)NN * 8 * 4);
  int* deg    = (int*)carve((size_t)(2 * NN + 192) * 4);  // deg|cursor|hist|boff|bcur
  int* cursor = deg + NN;
  int* hist   = deg + 2 * NN;
  int* boff   = hist + 64;
  int* bcur   = boff + 64;
  int* perm   = (int*)carve((size_t)NN * 4);
  int* offs   = (int*)carve((size_t)(NN + 1) * 4);
  int* bsum   = (int*)carve((size_t)32 * 4);
  int* csr    = (int*)carve((size_t)ET * 4);
  unsigned short* xbf  = (unsigned short*)carve((size_t)NN * 64 * 2);
  unsigned short* hbf0 = (unsigned short*)carve((size_t)NN * 256 * 2);
  unsigned short* hbf1 = (unsigned short*)carve((size_t)NN * 256 * 2);
  unsigned short* W0T  = (unsigned short*)carve((size_t)256 * 64 * 2);
  unsigned short* rW0T = (unsigned short*)carve((size_t)256 * 64 * 2);
  unsigned short* W1T  = (unsigned short*)carve((size_t)256 * 256 * 2);
  unsigned short* W2T  = (unsigned short*)carve((size_t)1024 * 256 * 2);
  unsigned short* rW2T = (unsigned short*)carve((size_t)128 * 256 * 2);
  size_t base = (size_t)(w - (char*)d_ws);
  if (ws_size < base) return;
  unsigned short* hG = (unsigned short*)bufH;   // bf16 h GEMM output alias

  size_t full_extra = (((size_t)16 * 256 * 2 + 255) & ~(size_t)255)
                    + (((size_t)128 * 2048 * 2 + 255) & ~(size_t)255)
                    + (((size_t)NN * 2048 * 2 + 255) & ~(size_t)255);
  size_t res2_extra = (((size_t)NN * 128 * 4 + 255) & ~(size_t)255);
  bool full = (ws_size - base) >= full_extra;
  unsigned short *V16 = nullptr, *WstkT = nullptr, *Ybuf = nullptr;
  if (full) {
    V16   = (unsigned short*)carve((size_t)16 * 256 * 2);
    WstkT = (unsigned short*)carve((size_t)128 * 2048 * 2);
    Ybuf  = (unsigned short*)carve((size_t)NN * 2048 * 2);
  }
  float* res2 = nullptr;
  if ((ws_size - (size_t)(w - (char*)d_ws)) >= res2_extra)
    res2 = (float*)carve((size_t)NN * 128 * 4);

  // ---- fused prep (cvt + transposes + V16/Wstk + zero deg/cursor/hist)
  prep_all<<<PREP_BLOCKS, 256, 0, stream>>>(x, xbf, W0, W0T, rW0, rW0T, W1, W1T,
                                            rW2, rW2T, W2, as2, ad2, V16, WstkT,
                                            deg, full ? 1 : 0);
  if (!full) tconv<<<1024, 256, 0, stream>>>(W2, W2T, 1024);

  // ---- CSR build + degree-sorted permutation
  count_kernel<<<(EE + 255) / 256, 256, 0, stream>>>(ei, deg);
  int nb = (NN + 1023) / 1024;
  scan_blk<<<nb, 1024, 0, stream>>>(deg, offs, bsum, hist);
  bucket_prefix<<<1, 64, 0, stream>>>(hist, boff);
  scan_add<<<(NN + 255) / 256, 256, 0, stream>>>(offs, bsum);
  perm_build<<<(NN + 255) / 256, 256, 0, stream>>>(offs, boff, bcur, perm);
  scatter_kernel<<<(ET + 255) / 256, 256, 0, stream>>>(ei, offs, cursor, csr);

  dim3 g256(4, (NN + 63) / 64);
  dim3 g128(2, (NN + 63) / 64);
  int gagg = (NN + 3) / 4;

  // ---- layer 0 (both GEMMs in one launch: z=0 h+logits, z=1 residual)
  gemm_l0<<<dim3(4, (NN + 63) / 64, 2), 256, 0, stream>>>(
      xbf, W0T, rW0T, rb0, hG, hbf1, as0, ad0, als, ald, NN);
  agg_epi_w<<<gagg, 256, 0, stream>>>(hG, als, ald, offs, csr, perm, b0, lng0,
                                      lnb0, hbf1, rw0, hbf0);

  // ---- layer 1 (residual = identity on hbf0)
  gemm_mfma_bf_al<<<g256, 256, 0, stream>>>(hbf0, W1T, hG, as1, ad1, als, ald, NN, 256);
  agg_epi_w<<<gagg, 256, 0, stream>>>(hG, als, ald, offs, csr, perm, b1, lng1,
                                      lnb1, hbf0, rw1, hbf1);   // hbf1 = hB

  // ---- layer 2
  if (full && res2) {
    gemm_l2a<<<dim3(3, (NN + 63) / 64), 256, 0, stream>>>(hbf1, V16, rW2T, rb2,
                                                          als, ald, res2, NN);
    agg_y_w<<<gagg, 256, 0, stream>>>(hbf1, als, ald, offs, csr, perm, Ybuf);
    float* partial = bufH;   // bufH+bufR contiguous, dead here
    gemm_y_tiled<<<dim3((NN + 63) / 64, 4), 256, 0, stream>>>(Ybuf, WstkT,
                                                              partial, NN);
    epi_out_res4<<<NN, 128, 0, stream>>>(partial, b2, lng2, lnb2, res2, rw2, outp);
  } else if (full) {
    gemm_al16<<<(NN + 63) / 64, 256, 0, stream>>>(hbf1, V16, als, ald, NN);
    agg_y_w<<<gagg, 256, 0, stream>>>(hbf1, als, ald, offs, csr, perm, Ybuf);
    gemm_mfma<<<g128, 256, 0, stream>>>(Ybuf, WstkT, nullptr, outp, NN, 2048, 128);
    epi_out_mv<<<NN, 128, 0, stream>>>(outp, b2, lng2, lnb2, hbf1, rW2, rb2, rw2);
  } else {
    if (res2)
      gemm_mfma<<<g128, 256, 0, stream>>>(hbf1, rW2T, rb2, res2, NN, 256, 128);
    zero_f32<<<(NN * 128 + 255) / 256, 256, 0, stream>>>(outp, NN * 128);
    for (int p = 0; p < 4; ++p) {
      gemm_mfma<<<g256, 256, 0, stream>>>(hbf1, W2T + (size_t)p * 256 * 256, nullptr,
                                          bufH, NN, 256, 256);
      al2<<<NN, 256, 0, stream>>>(bufH, as2 + p * 256, ad2 + p * 256, als, ald);
      agg2_pair<<<NN, 256, 0, stream>>>(bufH, als, ald, offs, csr, outp);
    }
    if (res2)
      epi_out_res<<<NN, 128, 0, stream>>>(outp, b2, lng2, lnb2, res2, rw2);
    else
      epi_out_mv<<<NN, 128, 0, stream>>>(outp, b2, lng2, lnb2, hbf1, rW2, rb2, rw2);
  }
}

// Round 16
// 393.371 us; speedup vs baseline: 1.1148x; 1.1148x over previous
//
#include <hip/hip_runtime.h>
#include <cstddef>
#include <cstdint>

#define NN 20000
#define EE 320000
#define ET (EE + NN)

typedef __attribute__((ext_vector_type(8))) short bf16x8;
typedef __attribute__((ext_vector_type(4))) float f32x4;

__device__ __forceinline__ unsigned short f2bf_rne(float f) {
  unsigned int u = __float_as_uint(f);
  u += 0x7FFF + ((u >> 16) & 1);
  return (unsigned short)(u >> 16);
}

__device__ __forceinline__ float bf2f(unsigned short b) {
  return __uint_as_float(((unsigned int)b) << 16);
}

__device__ __forceinline__ f32x4 up2(uint2 p) {
  f32x4 v = {__uint_as_float(p.x << 16), __uint_as_float(p.x & 0xFFFF0000u),
             __uint_as_float(p.y << 16), __uint_as_float(p.y & 0xFFFF0000u)};
  return v;
}

// ===================== fused prep: cvt + transposes + V16/Wstk + zero ============

__global__ __launch_bounds__(256) void prep_all(
    const float* __restrict__ x, unsigned short* __restrict__ xbf,
    const float* __restrict__ W0, unsigned short* __restrict__ W0T,
    const float* __restrict__ rW0, unsigned short* __restrict__ rW0T,
    const float* __restrict__ W1, unsigned short* __restrict__ W1T,
    const float* __restrict__ rW2, unsigned short* __restrict__ rW2T,
    const float* __restrict__ W2, const float* __restrict__ as2,
    const float* __restrict__ ad2, unsigned short* __restrict__ V16,
    unsigned short* __restrict__ WstkT, int* __restrict__ zbuf, int full) {
  int b = blockIdx.x, t = threadIdx.x;
  if (b < 5000) {
    int i = b * 256 + t;
    if (i < NN * 64) xbf[i] = f2bf_rne(x[i]);
    return;
  }
  b -= 5000;
  if (b < 64) {   // W0T: dst[n*64+k] = W0[k*256+n]
    int idx = b * 256 + t, n = idx >> 6, k = idx & 63;
    W0T[idx] = f2bf_rne(W0[(size_t)k * 256 + n]);
    return;
  }
  b -= 64;
  if (b < 64) {
    int idx = b * 256 + t, n = idx >> 6, k = idx & 63;
    rW0T[idx] = f2bf_rne(rW0[(size_t)k * 256 + n]);
    return;
  }
  b -= 64;
  if (b < 256) {  // W1T
    int idx = b * 256 + t, n = idx >> 8, k = idx & 255;
    W1T[idx] = f2bf_rne(W1[(size_t)k * 256 + n]);
    return;
  }
  b -= 256;
  if (b < 128) {  // rW2T
    int idx = b * 256 + t, n = idx >> 8, k = idx & 255;
    rW2T[idx] = f2bf_rne(rW2[(size_t)k * 128 + n]);
    return;
  }
  b -= 128;
  if (b < 157) {  // zero deg+cursor (2*NN ints)
    int i = b * 256 + t;
    if (i < 2 * NN) zbuf[i] = 0;
    return;
  }
  b -= 157;
  if (!full) return;
  if (b < 16) {   // V16 row b
    int r = b, k = t, h = r & 7;
    const float* av = (r < 8) ? (as2 + h * 128) : (ad2 + h * 128);
    const float* wr = W2 + (size_t)k * 1024 + h * 128;
    float v = 0.f;
#pragma unroll 4
    for (int c = 0; c < 128; ++c) v += wr[c] * av[c];
    V16[(size_t)r * 256 + k] = f2bf_rne(v);
    return;
  }
  b -= 16;
  if (b < 128) {  // WstkT col-block b
    int c = b, k = t;
#pragma unroll
    for (int h = 0; h < 8; ++h)
      WstkT[(size_t)c * 2048 + h * 256 + k] =
          f2bf_rne(0.125f * W2[(size_t)k * 1024 + h * 128 + c]);
  }
}

#define PREP_BLOCKS (5000 + 64 + 64 + 256 + 128 + 157 + 16 + 128)

// ===================== small utility / fallback kernels =====================

__global__ __launch_bounds__(256) void zero_f32(float* __restrict__ p, int n) {
  int i = blockIdx.x * 256 + threadIdx.x;
  if (i < n) p[i] = 0.f;
}

__global__ void tconv(const float* __restrict__ src, unsigned short* __restrict__ dst,
                      int N) {
  int n = blockIdx.x, k = threadIdx.x, K = blockDim.x;
  dst[(size_t)n * K + k] = f2bf_rne(src[(size_t)k * N + n]);
}

// ===================== CSR build (by dst, includes self loops) =====================

__global__ __launch_bounds__(256) void count_kernel(const int* __restrict__ ei,
                                                    int* __restrict__ deg) {
  int e = blockIdx.x * 256 + threadIdx.x;
  if (e < EE) {
    int d = ei[EE + e];
    if (d >= 0 && d < NN) atomicAdd(&deg[d], 1);
  }
}

__global__ __launch_bounds__(1024) void scan_blk(const int* __restrict__ deg,
    int* __restrict__ offs, int* __restrict__ bsum) {
  __shared__ int s[1024];
  int b = blockIdx.x, tid = threadIdx.x;
  int i = b * 1024 + tid;
  s[tid] = (i < NN) ? (deg[i] + 1) : 0;   // +1 = self loop
  __syncthreads();
  for (int off = 1; off < 1024; off <<= 1) {
    int t = (tid >= off) ? s[tid - off] : 0;
    __syncthreads();
    s[tid] += t;
    __syncthreads();
  }
  if (i < NN) offs[i + 1] = s[tid];
  if (tid == 1023) bsum[b] = s[1023];
}

__global__ __launch_bounds__(256) void scan_add(int* __restrict__ offs,
    const int* __restrict__ bsum) {
  int i = blockIdx.x * 256 + threadIdx.x;
  if (i == 0) offs[0] = 0;
  if (i < NN) {
    int b = i >> 10;
    int pre = 0;
    for (int k = 0; k < b; ++k) pre += bsum[k];
    offs[i + 1] += pre;
  }
}

__global__ __launch_bounds__(256) void scatter_kernel(const int* __restrict__ ei,
    const int* __restrict__ offs, int* __restrict__ cursor, int* __restrict__ csr) {
  int e = blockIdx.x * 256 + threadIdx.x;
  if (e >= ET) return;
  int s, d;
  if (e < EE) { s = ei[e]; d = ei[EE + e]; }
  else        { s = e - EE; d = s; }
  if (s < 0 || s >= NN || d < 0 || d >= NN) return;
  int pos = atomicAdd(&cursor[d], 1);
  csr[offs[d] + pos] = s;
}

// ===================== bf16 MFMA GEMM: C[M,N] = A[M,K] @ BT^T (+bias) =============

__global__ __launch_bounds__(256) void gemm_mfma(const unsigned short* __restrict__ A,
    const unsigned short* __restrict__ BT, const float* __restrict__ bias,
    float* __restrict__ C, int M, int K, int ldc) {
  int bm = blockIdx.y * 64, bn = blockIdx.x * 64;
  int tid = threadIdx.x;
  int w = tid >> 6, l = tid & 63;
  int wm = bm + w * 16;
  if (wm >= M) return;
  int lane16 = l & 15, q = l >> 4;
  const unsigned short* ap = A + (size_t)(wm + lane16) * K + q * 8;
  const unsigned short* bp = BT + (size_t)(bn + lane16) * K + q * 8;
  f32x4 acc0 = {0.f, 0.f, 0.f, 0.f}, acc1 = acc0, acc2 = acc0, acc3 = acc0;
#pragma unroll 2
  for (int k0 = 0; k0 < K; k0 += 32) {
    bf16x8 a  = *(const bf16x8*)(ap + k0);
    bf16x8 b0 = *(const bf16x8*)(bp + k0);
    bf16x8 b1 = *(const bf16x8*)(bp + (size_t)16 * K + k0);
    bf16x8 b2 = *(const bf16x8*)(bp + (size_t)32 * K + k0);
    bf16x8 b3 = *(const bf16x8*)(bp + (size_t)48 * K + k0);
    acc0 = __builtin_amdgcn_mfma_f32_16x16x32_bf16(a, b0, acc0, 0, 0, 0);
    acc1 = __builtin_amdgcn_mfma_f32_16x16x32_bf16(a, b1, acc1, 0, 0, 0);
    acc2 = __builtin_amdgcn_mfma_f32_16x16x32_bf16(a, b2, acc2, 0, 0, 0);
    acc3 = __builtin_amdgcn_mfma_f32_16x16x32_bf16(a, b3, acc3, 0, 0, 0);
  }
  int row0 = wm + q * 4;
  int c0 = bn + lane16;
  float bi0 = bias ? bias[c0]      : 0.f;
  float bi1 = bias ? bias[c0 + 16] : 0.f;
  float bi2 = bias ? bias[c0 + 32] : 0.f;
  float bi3 = bias ? bias[c0 + 48] : 0.f;
#pragma unroll
  for (int r = 0; r < 4; ++r) {
    float* crow = C + (size_t)(row0 + r) * ldc;
    crow[c0]      = acc0[r] + bi0;
    crow[c0 + 16] = acc1[r] + bi1;
    crow[c0 + 32] = acc2[r] + bi2;
    crow[c0 + 48] = acc3[r] + bi3;
  }
}

// fused layer-0 GEMMs: z=0 -> h(bf16)+logits; z=1 -> residual bf16+bias.  K=64.
__global__ __launch_bounds__(256) void gemm_l0(const unsigned short* __restrict__ A,
    const unsigned short* __restrict__ W0T, const unsigned short* __restrict__ rW0T,
    const float* __restrict__ rb0, unsigned short* __restrict__ hG,
    unsigned short* __restrict__ resout, const float* __restrict__ as_w,
    const float* __restrict__ ad_w, float* __restrict__ als,
    float* __restrict__ ald, int M) {
  int z = blockIdx.z;
  int bm = blockIdx.y * 64, bn = blockIdx.x * 64;
  int tid = threadIdx.x;
  int w = tid >> 6, l = tid & 63;
  int wm = bm + w * 16;
  if (wm >= M) return;
  int lane16 = l & 15, q = l >> 4;
  const unsigned short* BT = z ? rW0T : W0T;
  const unsigned short* ap = A + (size_t)(wm + lane16) * 64 + q * 8;
  const unsigned short* bp = BT + (size_t)(bn + lane16) * 64 + q * 8;
  f32x4 acc0 = {0.f, 0.f, 0.f, 0.f}, acc1 = acc0, acc2 = acc0, acc3 = acc0;
#pragma unroll
  for (int k0 = 0; k0 < 64; k0 += 32) {
    bf16x8 a  = *(const bf16x8*)(ap + k0);
    bf16x8 b0 = *(const bf16x8*)(bp + k0);
    bf16x8 b1 = *(const bf16x8*)(bp + (size_t)16 * 64 + k0);
    bf16x8 b2 = *(const bf16x8*)(bp + (size_t)32 * 64 + k0);
    bf16x8 b3 = *(const bf16x8*)(bp + (size_t)48 * 64 + k0);
    acc0 = __builtin_amdgcn_mfma_f32_16x16x32_bf16(a, b0, acc0, 0, 0, 0);
    acc1 = __builtin_amdgcn_mfma_f32_16x16x32_bf16(a, b1, acc1, 0, 0, 0);
    acc2 = __builtin_amdgcn_mfma_f32_16x16x32_bf16(a, b2, acc2, 0, 0, 0);
    acc3 = __builtin_amdgcn_mfma_f32_16x16x32_bf16(a, b3, acc3, 0, 0, 0);
  }
  int row0 = wm + q * 4;
  int c0 = bn + lane16;
  if (z == 1) {
    float bi0 = rb0[c0], bi1 = rb0[c0 + 16], bi2 = rb0[c0 + 32], bi3 = rb0[c0 + 48];
#pragma unroll
    for (int r = 0; r < 4; ++r) {
      unsigned short* crow = resout + (size_t)(row0 + r) * 256;
      crow[c0]      = f2bf_rne(acc0[r] + bi0);
      crow[c0 + 16] = f2bf_rne(acc1[r] + bi1);
      crow[c0 + 32] = f2bf_rne(acc2[r] + bi2);
      crow[c0 + 48] = f2bf_rne(acc3[r] + bi3);
    }
    return;
  }
#pragma unroll
  for (int r = 0; r < 4; ++r) {
    unsigned short* crow = hG + (size_t)(row0 + r) * 256;
    crow[c0]      = f2bf_rne(acc0[r]);
    crow[c0 + 16] = f2bf_rne(acc1[r]);
    crow[c0 + 32] = f2bf_rne(acc2[r]);
    crow[c0 + 48] = f2bf_rne(acc3[r]);
  }
  float asA0 = as_w[c0],      asA1 = as_w[c0 + 16];
  float adA0 = ad_w[c0],      adA1 = ad_w[c0 + 16];
  float asB0 = as_w[c0 + 32], asB1 = as_w[c0 + 48];
  float adB0 = ad_w[c0 + 32], adB1 = ad_w[c0 + 48];
  int hA = (bn >> 5), hB = hA + 1;
#pragma unroll
  for (int r = 0; r < 4; ++r) {
    float sA = acc0[r] * asA0 + acc1[r] * asA1;
    float dA = acc0[r] * adA0 + acc1[r] * adA1;
    float sB = acc2[r] * asB0 + acc3[r] * asB1;
    float dB = acc2[r] * adB0 + acc3[r] * adB1;
#pragma unroll
    for (int off = 8; off >= 1; off >>= 1) {
      sA += __shfl_xor(sA, off);
      dA += __shfl_xor(dA, off);
      sB += __shfl_xor(sB, off);
      dB += __shfl_xor(dB, off);
    }
    if (lane16 == 0) {
      int row = row0 + r;
      als[row * 8 + hA] = sA;
      ald[row * 8 + hA] = dA;
      als[row * 8 + hB] = sB;
      ald[row * 8 + hB] = dB;
    }
  }
}

// bf16-out h GEMM with FUSED attention logits (layer 1, K=256)
__global__ __launch_bounds__(256) void gemm_mfma_bf_al(const unsigned short* __restrict__ A,
    const unsigned short* __restrict__ BT, unsigned short* __restrict__ C,
    const float* __restrict__ as_w, const float* __restrict__ ad_w,
    float* __restrict__ als, float* __restrict__ ald, int M, int K) {
  int bm = blockIdx.y * 64, bn = blockIdx.x * 64;
  int tid = threadIdx.x;
  int w = tid >> 6, l = tid & 63;
  int wm = bm + w * 16;
  if (wm >= M) return;
  int lane16 = l & 15, q = l >> 4;
  const unsigned short* ap = A + (size_t)(wm + lane16) * K + q * 8;
  const unsigned short* bp = BT + (size_t)(bn + lane16) * K + q * 8;
  f32x4 acc0 = {0.f, 0.f, 0.f, 0.f}, acc1 = acc0, acc2 = acc0, acc3 = acc0;
#pragma unroll 2
  for (int k0 = 0; k0 < K; k0 += 32) {
    bf16x8 a  = *(const bf16x8*)(ap + k0);
    bf16x8 b0 = *(const bf16x8*)(bp + k0);
    bf16x8 b1 = *(const bf16x8*)(bp + (size_t)16 * K + k0);
    bf16x8 b2 = *(const bf16x8*)(bp + (size_t)32 * K + k0);
    bf16x8 b3 = *(const bf16x8*)(bp + (size_t)48 * K + k0);
    acc0 = __builtin_amdgcn_mfma_f32_16x16x32_bf16(a, b0, acc0, 0, 0, 0);
    acc1 = __builtin_amdgcn_mfma_f32_16x16x32_bf16(a, b1, acc1, 0, 0, 0);
    acc2 = __builtin_amdgcn_mfma_f32_16x16x32_bf16(a, b2, acc2, 0, 0, 0);
    acc3 = __builtin_amdgcn_mfma_f32_16x16x32_bf16(a, b3, acc3, 0, 0, 0);
  }
  int row0 = wm + q * 4;
  int c0 = bn + lane16;
#pragma unroll
  for (int r = 0; r < 4; ++r) {
    unsigned short* crow = C + (size_t)(row0 + r) * 256;
    crow[c0]      = f2bf_rne(acc0[r]);
    crow[c0 + 16] = f2bf_rne(acc1[r]);
    crow[c0 + 32] = f2bf_rne(acc2[r]);
    crow[c0 + 48] = f2bf_rne(acc3[r]);
  }
  float asA0 = as_w[c0],      asA1 = as_w[c0 + 16];
  float adA0 = ad_w[c0],      adA1 = ad_w[c0 + 16];
  float asB0 = as_w[c0 + 32], asB1 = as_w[c0 + 48];
  float adB0 = ad_w[c0 + 32], adB1 = ad_w[c0 + 48];
  int hA = (bn >> 5), hB = hA + 1;
#pragma unroll
  for (int r = 0; r < 4; ++r) {
    float sA = acc0[r] * asA0 + acc1[r] * asA1;
    float dA = acc0[r] * adA0 + acc1[r] * adA1;
    float sB = acc2[r] * asB0 + acc3[r] * asB1;
    float dB = acc2[r] * adB0 + acc3[r] * adB1;
#pragma unroll
    for (int off = 8; off >= 1; off >>= 1) {
      sA += __shfl_xor(sA, off);
      dA += __shfl_xor(dA, off);
      sB += __shfl_xor(sB, off);
      dB += __shfl_xor(dB, off);
    }
    if (lane16 == 0) {
      int row = row0 + r;
      als[row * 8 + hA] = sA;
      ald[row * 8 + hA] = dA;
      als[row * 8 + hB] = sB;
      ald[row * 8 + hB] = dB;
    }
  }
}

// fused layer-2 small GEMMs: x=0 -> al16 logits; x=1,2 -> res2 (N=128, fp32+bias)
__global__ __launch_bounds__(256) void gemm_l2a(const unsigned short* __restrict__ A,
    const unsigned short* __restrict__ V16, const unsigned short* __restrict__ rW2T,
    const float* __restrict__ rb2, float* __restrict__ als, float* __restrict__ ald,
    float* __restrict__ res2, int M) {
  int bx = blockIdx.x;
  int bm = blockIdx.y * 64;
  int tid = threadIdx.x;
  int w = tid >> 6, l = tid & 63;
  int wm = bm + w * 16;
  if (wm >= M) return;
  int lane16 = l & 15, q = l >> 4;
  const unsigned short* ap = A + (size_t)(wm + lane16) * 256 + q * 8;
  if (bx == 0) {
    const unsigned short* bp = V16 + (size_t)lane16 * 256 + q * 8;
    f32x4 acc = {0.f, 0.f, 0.f, 0.f};
#pragma unroll
    for (int k0 = 0; k0 < 256; k0 += 32) {
      bf16x8 a = *(const bf16x8*)(ap + k0);
      bf16x8 b = *(const bf16x8*)(bp + k0);
      acc = __builtin_amdgcn_mfma_f32_16x16x32_bf16(a, b, acc, 0, 0, 0);
    }
    int row0 = wm + q * 4;
    float* dst = (lane16 < 8) ? als : ald;
    int h = lane16 & 7;
#pragma unroll
    for (int r = 0; r < 4; ++r)
      dst[(size_t)(row0 + r) * 8 + h] = acc[r];
    return;
  }
  int bn = (bx - 1) * 64;
  const unsigned short* bp = rW2T + (size_t)(bn + lane16) * 256 + q * 8;
  f32x4 acc0 = {0.f, 0.f, 0.f, 0.f}, acc1 = acc0, acc2 = acc0, acc3 = acc0;
#pragma unroll 2
  for (int k0 = 0; k0 < 256; k0 += 32) {
    bf16x8 a  = *(const bf16x8*)(ap + k0);
    bf16x8 b0 = *(const bf16x8*)(bp + k0);
    bf16x8 b1 = *(const bf16x8*)(bp + (size_t)16 * 256 + k0);
    bf16x8 b2 = *(const bf16x8*)(bp + (size_t)32 * 256 + k0);
    bf16x8 b3 = *(const bf16x8*)(bp + (size_t)48 * 256 + k0);
    acc0 = __builtin_amdgcn_mfma_f32_16x16x32_bf16(a, b0, acc0, 0, 0, 0);
    acc1 = __builtin_amdgcn_mfma_f32_16x16x32_bf16(a, b1, acc1, 0, 0, 0);
    acc2 = __builtin_amdgcn_mfma_f32_16x16x32_bf16(a, b2, acc2, 0, 0, 0);
    acc3 = __builtin_amdgcn_mfma_f32_16x16x32_bf16(a, b3, acc3, 0, 0, 0);
  }
  int row0 = wm + q * 4;
  int c0 = bn + lane16;
  float bi0 = rb2[c0], bi1 = rb2[c0 + 16], bi2 = rb2[c0 + 32], bi3 = rb2[c0 + 48];
#pragma unroll
  for (int r = 0; r < 4; ++r) {
    float* crow = res2 + (size_t)(row0 + r) * 128;
    crow[c0]      = acc0[r] + bi0;
    crow[c0 + 16] = acc1[r] + bi1;
    crow[c0 + 32] = acc2[r] + bi2;
    crow[c0 + 48] = acc3[r] + bi3;
  }
}

// standalone al16 (used when res2 buffer is absent)
__global__ __launch_bounds__(256) void gemm_al16(const unsigned short* __restrict__ A,
    const unsigned short* __restrict__ V16, float* __restrict__ als,
    float* __restrict__ ald, int M) {
  int bm = blockIdx.x * 64;
  int tid = threadIdx.x;
  int w = tid >> 6, l = tid & 63;
  int wm = bm + w * 16;
  if (wm >= M) return;
  int lane16 = l & 15, q = l >> 4;
  const unsigned short* ap = A + (size_t)(wm + lane16) * 256 + q * 8;
  const unsigned short* bp = V16 + (size_t)lane16 * 256 + q * 8;
  f32x4 acc = {0.f, 0.f, 0.f, 0.f};
#pragma unroll
  for (int k0 = 0; k0 < 256; k0 += 32) {
    bf16x8 a = *(const bf16x8*)(ap + k0);
    bf16x8 b = *(const bf16x8*)(bp + k0);
    acc = __builtin_amdgcn_mfma_f32_16x16x32_bf16(a, b, acc, 0, 0, 0);
  }
  int row0 = wm + q * 4;
  float* dst = (lane16 < 8) ? als : ald;
  int h = lane16 & 7;
#pragma unroll
  for (int r = 0; r < 4; ++r)
    dst[(size_t)(row0 + r) * 8 + h] = acc[r];
}

// ===================== LDS-tiled split-K Y GEMM ==================================

__global__ __launch_bounds__(256) void gemm_y_tiled(const unsigned short* __restrict__ A,
    const unsigned short* __restrict__ BT, float* __restrict__ P, int M) {
  __shared__ unsigned short sA[64][72];
  __shared__ unsigned short sB[128][72];
  int bm = blockIdx.x * 64, s = blockIdx.y;
  int tid = threadIdx.x;
  int w = tid >> 6, l = tid & 63;
  int lane16 = l & 15, q = l >> 4;
  int soff = s * 512;
  int r = tid >> 3, c = (tid & 7) * 8;
  int rA0 = min(bm + r, M - 1);
  int rA1 = min(bm + r + 32, M - 1);
  f32x4 acc[8] = {};
#pragma unroll 1
  for (int kt = 0; kt < 8; ++kt) {
    int kb = soff + kt * 64 + c;
    *(bf16x8*)&sA[r][c]      = *(const bf16x8*)(A + (size_t)rA0 * 2048 + kb);
    *(bf16x8*)&sA[r + 32][c] = *(const bf16x8*)(A + (size_t)rA1 * 2048 + kb);
#pragma unroll
    for (int rr = 0; rr < 4; ++rr)
      *(bf16x8*)&sB[r + rr * 32][c] = *(const bf16x8*)(BT + (size_t)(r + rr * 32) * 2048 + kb);
    __syncthreads();
#pragma unroll
    for (int kk = 0; kk < 2; ++kk) {
      bf16x8 a = *(const bf16x8*)&sA[w * 16 + lane16][kk * 32 + q * 8];
#pragma unroll
      for (int t = 0; t < 8; ++t) {
        bf16x8 b = *(const bf16x8*)&sB[t * 16 + lane16][kk * 32 + q * 8];
        acc[t] = __builtin_amdgcn_mfma_f32_16x16x32_bf16(a, b, acc[t], 0, 0, 0);
      }
    }
    __syncthreads();
  }
  int row0 = bm + w * 16 + q * 4;
  float* pbase = P + (size_t)s * ((size_t)M * 128);
#pragma unroll
  for (int r2 = 0; r2 < 4; ++r2) {
    if (row0 + r2 < M) {
      float* prow = pbase + (size_t)(row0 + r2) * 128 + lane16;
#pragma unroll
      for (int t = 0; t < 8; ++t) prow[t * 16] = acc[t][r2];
    }
  }
}

// ===================== attention logits (fallback path only) =====================

__global__ __launch_bounds__(256) void al2(const float* __restrict__ h,
    const float* __restrict__ aw_s, const float* __restrict__ aw_d,
    float* __restrict__ als, float* __restrict__ ald) {
  int n = blockIdx.x, tid = threadIdx.x;
  int j = tid & 127;
  __shared__ float ss[256], sd[256];
  float v = h[(size_t)n * 256 + tid];
  ss[tid] = v * aw_s[tid];
  sd[tid] = v * aw_d[tid];
  __syncthreads();
  for (int off = 64; off > 0; off >>= 1) {
    if (j < off) { ss[tid] += ss[tid + off]; sd[tid] += sd[tid + off]; }
    __syncthreads();
  }
  if (j == 0) {
    int hh = tid >> 7;
    als[n * 2 + hh] = ss[tid];
    ald[n * 2 + hh] = sd[tid];
  }
}

// ===================== wave-per-node agg + LN + residual + ELU, layers 0/1 ========

__global__ __launch_bounds__(256) void agg_epi_w(const unsigned short* __restrict__ hG,
    const float* __restrict__ als, const float* __restrict__ ald,
    const int* __restrict__ offs, const int* __restrict__ csr,
    const float* __restrict__ bias, const float* __restrict__ lng,
    const float* __restrict__ lnb, const unsigned short* __restrict__ resb,
    const float* __restrict__ rw, unsigned short* __restrict__ outbf) {
  int w = threadIdx.x >> 6, l = threadIdx.x & 63;
  int n = blockIdx.x * 4 + w;
  if (n >= NN) return;
  int r0 = offs[n], r1 = offs[n + 1], deg = r1 - r0;
  int h8 = l & 7, e8 = l >> 3, hl = l >> 3;
  float aldn = ald[n * 8 + h8];
  f32x4 acc = {0.f, 0.f, 0.f, 0.f};
  float denacc = 0.f;
  for (int c0 = 0; c0 < deg; c0 += 8) {
    int cn = min(8, deg - c0);
    int src_my = csr[r0 + c0 + min(e8, cn - 1)];
    float ev = als[src_my * 8 + h8] + aldn;
    ev = ev >= 0.f ? ev : 0.2f * ev;
    float aexp = (e8 < cn) ? __expf(ev) : 0.f;
    denacc += aexp;
#pragma unroll 2
    for (int e = 0; e < cn; ++e) {
      int s = __shfl(src_my, e * 8);
      float a = __shfl(aexp, e * 8 + hl);
      uint2 p = *(const uint2*)(hG + (size_t)s * 256 + l * 4);
      acc += a * up2(p);
    }
  }
  denacc += __shfl_xor(denacc, 8);
  denacc += __shfl_xor(denacc, 16);
  denacc += __shfl_xor(denacc, 32);
  float den = __shfl(denacc, hl);
  float dinv = 1.f / (den + 1e-16f);
  float4 bi = ((const float4*)bias)[l];
  uint2 pb = ((const uint2*)resb)[(size_t)n * 64 + l];
  f32x4 rr = up2(pb);
  f32x4 val = {acc.x * dinv + bi.x, acc.y * dinv + bi.y,
               acc.z * dinv + bi.z, acc.w * dinv + bi.w};
  float v1 = val.x + val.y + val.z + val.w;
  float v2 = val.x * val.x + val.y * val.y + val.z * val.z + val.w * val.w;
#pragma unroll
  for (int off = 32; off >= 1; off >>= 1) {
    v1 += __shfl_xor(v1, off);
    v2 += __shfl_xor(v2, off);
  }
  float mu = v1 * (1.f / 256.f);
  float var = v2 * (1.f / 256.f) - mu * mu;
  float rs = rsqrtf(var + 1e-5f);
  float sig = 1.f / (1.f + __expf(-rw[0]));
  float4 lg = ((const float4*)lng)[l];
  float4 lb = ((const float4*)lnb)[l];
  float ov[4];
  const float* valp = (const float*)&val;
  const float* rrp = (const float*)&rr;
  const float* lgp = &lg.x;
  const float* lbp = &lb.x;
#pragma unroll
  for (int k = 0; k < 4; ++k) {
    float rv = (valp[k] - mu) * rs * lgp[k] + lbp[k] + sig * rrp[k];
    ov[k] = rv > 0.f ? rv : (__expf(rv) - 1.f);
  }
  uint2 pk;
  pk.x = (unsigned)f2bf_rne(ov[0]) | ((unsigned)f2bf_rne(ov[1]) << 16);
  pk.y = (unsigned)f2bf_rne(ov[2]) | ((unsigned)f2bf_rne(ov[3]) << 16);
  ((uint2*)outbf)[(size_t)n * 64 + l] = pk;
}

// ===================== wave-per-node layer-2 aggregation ==========================

__global__ __launch_bounds__(256) void agg_y_w(const unsigned short* __restrict__ hbf,
    const float* __restrict__ als, const float* __restrict__ ald,
    const int* __restrict__ offs, const int* __restrict__ csr,
    unsigned short* __restrict__ Y) {
  int w = threadIdx.x >> 6, l = threadIdx.x & 63;
  int n = blockIdx.x * 4 + w;
  if (n >= NN) return;
  int r0 = offs[n], r1 = offs[n + 1], deg = r1 - r0;
  int h8 = l & 7, e8 = l >> 3;
  float aldn = ald[n * 8 + h8];
  f32x4 accv[8] = {};
  float denacc = 0.f;
  for (int c0 = 0; c0 < deg; c0 += 8) {
    int cn = min(8, deg - c0);
    int src_my = csr[r0 + c0 + min(e8, cn - 1)];
    float ev = als[src_my * 8 + h8] + aldn;
    ev = ev >= 0.f ? ev : 0.2f * ev;
    float aexp = (e8 < cn) ? __expf(ev) : 0.f;
    denacc += aexp;
    for (int e = 0; e < cn; ++e) {
      int s = __shfl(src_my, e * 8);
      uint2 p = *(const uint2*)(hbf + (size_t)s * 256 + l * 4);
      f32x4 v = up2(p);
#pragma unroll
      for (int h = 0; h < 8; ++h) {
        float a = __shfl(aexp, e * 8 + h);
        accv[h] += a * v;
      }
    }
  }
  denacc += __shfl_xor(denacc, 8);
  denacc += __shfl_xor(denacc, 16);
  denacc += __shfl_xor(denacc, 32);
  unsigned short* yrow = Y + (size_t)n * 2048;
#pragma unroll
  for (int h = 0; h < 8; ++h) {
    float dh = __shfl(denacc, h);
    float sc = 1.f / (dh + 1e-16f);
    f32x4 t = accv[h];
    uint2 pk;
    pk.x = (unsigned)f2bf_rne(t.x * sc) | ((unsigned)f2bf_rne(t.y * sc) << 16);
    pk.y = (unsigned)f2bf_rne(t.z * sc) | ((unsigned)f2bf_rne(t.w * sc) << 16);
    *(uint2*)(yrow + h * 256 + l * 4) = pk;
  }
}

// ===================== fallback layer-2 pair aggregation (round-4 path) ===========

__global__ __launch_bounds__(256) void agg2_pair(const float* __restrict__ h2,
    const float* __restrict__ als, const float* __restrict__ ald,
    const int* __restrict__ offs, const int* __restrict__ csr,
    float* __restrict__ acc_out) {
  int n = blockIdx.x, tid = threadIdx.x;
  int r0 = offs[n], r1 = offs[n + 1];
  __shared__ float s_red[256];
  __shared__ float s_dn[2];
  int hh = tid >> 7, j = tid & 127;
  float aldn = ald[n * 2 + hh];
  float sm = 0.f;
  for (int i = r0 + j; i < r1; i += 128) {
    int s = csr[i];
    float ev = als[s * 2 + hh] + aldn;
    ev = ev >= 0.f ? ev : 0.2f * ev;
    sm += __expf(ev);
  }
  s_red[tid] = sm;
  __syncthreads();
  for (int off = 64; off > 0; off >>= 1) {
    if (j < off) s_red[tid] += s_red[tid + off];
    __syncthreads();
  }
  if (j == 0) s_dn[hh] = s_red[tid] + 1e-16f;
  __syncthreads();
  float dinv = 1.f / s_dn[hh];
  float acc = 0.f;
  for (int i = r0; i < r1; ++i) {
    int s = csr[i];
    float ev = als[s * 2 + hh] + aldn;
    ev = ev >= 0.f ? ev : 0.2f * ev;
    float alpha = __expf(ev) * dinv;
    acc += alpha * h2[(size_t)s * 256 + tid];
  }
  s_red[tid] = acc;
  __syncthreads();
  if (tid < 128)
    acc_out[(size_t)n * 128 + tid] += 0.125f * (s_red[tid] + s_red[tid + 128]);
}

// ===================== layer-2 epilogues ====================

__global__ __launch_bounds__(128) void epi_out_res4(const float* __restrict__ P,
    const float* __restrict__ b2, const float* __restrict__ lng,
    const float* __restrict__ lnb, const float* __restrict__ res2,
    const float* __restrict__ rw, float* __restrict__ out) {
  int n = blockIdx.x, tid = threadIdx.x;
  __shared__ float sw1[2], sw2[2];
  size_t stride = (size_t)NN * 128;
  size_t idx = (size_t)n * 128 + tid;
  float g = P[idx] + P[stride + idx] + P[2 * stride + idx] + P[3 * stride + idx] + b2[tid];
  float v1 = g, v2 = g * g;
#pragma unroll
  for (int off = 32; off >= 1; off >>= 1) {
    v1 += __shfl_xor(v1, off);
    v2 += __shfl_xor(v2, off);
  }
  if ((tid & 63) == 0) { sw1[tid >> 6] = v1; sw2[tid >> 6] = v2; }
  __syncthreads();
  float tot1 = sw1[0] + sw1[1], tot2 = sw2[0] + sw2[1];
  float mu = tot1 * (1.f / 128.f);
  float var = tot2 * (1.f / 128.f) - mu * mu;
  float rs = rsqrtf(var + 1e-5f);
  float sig = 1.f / (1.f + __expf(-rw[0]));
  out[idx] = (g - mu) * rs * lng[tid] + lnb[tid] + sig * res2[idx];
}

__global__ __launch_bounds__(128) void epi_out_res(float* __restrict__ acc,
    const float* __restrict__ b2, const float* __restrict__ lng,
    const float* __restrict__ lnb, const float* __restrict__ res2,
    const float* __restrict__ rw) {
  int n = blockIdx.x, tid = threadIdx.x;
  __shared__ float s1[128], s2[128];
  __shared__ float s_mu, s_rs;
  float g = acc[(size_t)n * 128 + tid] + b2[tid];
  s1[tid] = g; s2[tid] = g * g;
  __syncthreads();
  for (int off = 64; off > 0; off >>= 1) {
    if (tid < off) { s1[tid] += s1[tid + off]; s2[tid] += s2[tid + off]; }
    __syncthreads();
  }
  if (tid == 0) {
    float mu = s1[0] * (1.f / 128.f);
    float var = s2[0] * (1.f / 128.f) - mu * mu;
    s_mu = mu; s_rs = rsqrtf(var + 1e-5f);
  }
  __syncthreads();
  float sig = 1.f / (1.f + __expf(-rw[0]));
  float lnv = (g - s_mu) * s_rs * lng[tid] + lnb[tid];
  acc[(size_t)n * 128 + tid] = lnv + sig * res2[(size_t)n * 128 + tid];
}

__global__ __launch_bounds__(128) void epi_out_mv(float* __restrict__ acc,
    const float* __restrict__ b2, const float* __restrict__ lng,
    const float* __restrict__ lnb, const unsigned short* __restrict__ hB,
    const float* __restrict__ rW2, const float* __restrict__ rb2,
    const float* __restrict__ rw) {
  int n = blockIdx.x, tid = threadIdx.x;
  __shared__ float srow[256];
  __shared__ float s1[128], s2[128];
  __shared__ float s_mu, s_rs;
  srow[tid] = bf2f(hB[(size_t)n * 256 + tid]);
  srow[tid + 128] = bf2f(hB[(size_t)n * 256 + tid + 128]);
  float g = acc[(size_t)n * 128 + tid] + b2[tid];
  s1[tid] = g; s2[tid] = g * g;
  __syncthreads();
  for (int off = 64; off > 0; off >>= 1) {
    if (tid < off) { s1[tid] += s1[tid + off]; s2[tid] += s2[tid + off]; }
    __syncthreads();
  }
  if (tid == 0) {
    float mu = s1[0] * (1.f / 128.f);
    float var = s2[0] * (1.f / 128.f) - mu * mu;
    s_mu = mu; s_rs = rsqrtf(var + 1e-5f);
  }
  __syncthreads();
  float rv = rb2[tid];
#pragma unroll 4
  for (int k = 0; k < 256; ++k) rv += srow[k] * rW2[(size_t)k * 128 + tid];
  float sig = 1.f / (1.f + __expf(-rw[0]));
  float lnv = (g - s_mu) * s_rs * lng[tid] + lnb[tid];
  acc[(size_t)n * 128 + tid] = lnv + sig * rv;
}

// ===================== launch ====================================================

extern "C" void kernel_launch(void* const* d_in, const int* in_sizes, int n_in,
                              void* d_out, int out_size, void* d_ws, size_t ws_size,
                              hipStream_t stream) {
  const float* x   = (const float*)d_in[0];
  const int*   ei  = (const int*)d_in[1];   // int64 in reference -> int32 on device
  const float* W0  = (const float*)d_in[2];
  const float* b0  = (const float*)d_in[3];
  const float* as0 = (const float*)d_in[4];
  const float* ad0 = (const float*)d_in[5];
  const float* lng0= (const float*)d_in[6];
  const float* lnb0= (const float*)d_in[7];
  const float* rW0 = (const float*)d_in[8];
  const float* rb0 = (const float*)d_in[9];
  const float* rw0 = (const float*)d_in[10];
  const float* W1  = (const float*)d_in[11];
  const float* b1  = (const float*)d_in[12];
  const float* as1 = (const float*)d_in[13];
  const float* ad1 = (const float*)d_in[14];
  const float* lng1= (const float*)d_in[15];
  const float* lnb1= (const float*)d_in[16];
  const float* rw1 = (const float*)d_in[17];
  const float* W2  = (const float*)d_in[18];
  const float* b2  = (const float*)d_in[19];
  const float* as2 = (const float*)d_in[20];
  const float* ad2 = (const float*)d_in[21];
  const float* lng2= (const float*)d_in[22];
  const float* lnb2= (const float*)d_in[23];
  const float* rW2 = (const float*)d_in[24];
  const float* rb2 = (const float*)d_in[25];
  const float* rw2 = (const float*)d_in[26];
  float* outp = (float*)d_out;

  char* w = (char*)d_ws;
  auto carve = [&](size_t bytes) -> char* {
    char* p = w;
    w += (bytes + 255) & ~(size_t)255;
    return p;
  };
  // bufH+bufR contiguous; dead during layer 2 (res2 path) -> 40.96 MB split-K partials
  float* bufH = (float*)carve((size_t)NN * 256 * 4);
  float* bufR = (float*)carve((size_t)NN * 256 * 4);
  float* als  = (float*)carve((size_t)NN * 8 * 4);
  float* ald  = (float*)carve((size_t)NN * 8 * 4);
  int* deg    = (int*)carve((size_t)2 * NN * 4);   // deg + cursor
  int* cursor = deg + NN;
  int* offs   = (int*)carve((size_t)(NN + 1) * 4);
  int* bsum   = (int*)carve((size_t)32 * 4);
  int* csr    = (int*)carve((size_t)ET * 4);
  unsigned short* xbf  = (unsigned short*)carve((size_t)NN * 64 * 2);
  unsigned short* hbf0 = (unsigned short*)carve((size_t)NN * 256 * 2);
  unsigned short* hbf1 = (unsigned short*)carve((size_t)NN * 256 * 2);
  unsigned short* W0T  = (unsigned short*)carve((size_t)256 * 64 * 2);
  unsigned short* rW0T = (unsigned short*)carve((size_t)256 * 64 * 2);
  unsigned short* W1T  = (unsigned short*)carve((size_t)256 * 256 * 2);
  unsigned short* W2T  = (unsigned short*)carve((size_t)1024 * 256 * 2);
  unsigned short* rW2T = (unsigned short*)carve((size_t)128 * 256 * 2);
  size_t base = (size_t)(w - (char*)d_ws);
  if (ws_size < base) return;
  unsigned short* hG = (unsigned short*)bufH;   // bf16 h GEMM output alias

  size_t full_extra = (((size_t)16 * 256 * 2 + 255) & ~(size_t)255)
                    + (((size_t)128 * 2048 * 2 + 255) & ~(size_t)255)
                    + (((size_t)NN * 2048 * 2 + 255) & ~(size_t)255);
  size_t res2_extra = (((size_t)NN * 128 * 4 + 255) & ~(size_t)255);
  bool full = (ws_size - base) >= full_extra;
  unsigned short *V16 = nullptr, *WstkT = nullptr, *Ybuf = nullptr;
  if (full) {
    V16   = (unsigned short*)carve((size_t)16 * 256 * 2);
    WstkT = (unsigned short*)carve((size_t)128 * 2048 * 2);
    Ybuf  = (unsigned short*)carve((size_t)NN * 2048 * 2);
  }
  float* res2 = nullptr;
  if ((ws_size - (size_t)(w - (char*)d_ws)) >= res2_extra)
    res2 = (float*)carve((size_t)NN * 128 * 4);

  // ---- fused prep (cvt + transposes + V16/Wstk + zero deg/cursor)
  prep_all<<<PREP_BLOCKS, 256, 0, stream>>>(x, xbf, W0, W0T, rW0, rW0T, W1, W1T,
                                            rW2, rW2T, W2, as2, ad2, V16, WstkT,
                                            deg, full ? 1 : 0);
  if (!full) tconv<<<1024, 256, 0, stream>>>(W2, W2T, 1024);

  // ---- CSR build
  count_kernel<<<(EE + 255) / 256, 256, 0, stream>>>(ei, deg);
  int nb = (NN + 1023) / 1024;
  scan_blk<<<nb, 1024, 0, stream>>>(deg, offs, bsum);
  scan_add<<<(NN + 255) / 256, 256, 0, stream>>>(offs, bsum);
  scatter_kernel<<<(ET + 255) / 256, 256, 0, stream>>>(ei, offs, cursor, csr);

  dim3 g256(4, (NN + 63) / 64);
  dim3 g128(2, (NN + 63) / 64);
  int gagg = (NN + 3) / 4;

  // ---- layer 0 (both GEMMs in one launch: z=0 h+logits, z=1 residual)
  gemm_l0<<<dim3(4, (NN + 63) / 64, 2), 256, 0, stream>>>(
      xbf, W0T, rW0T, rb0, hG, hbf1, as0, ad0, als, ald, NN);
  agg_epi_w<<<gagg, 256, 0, stream>>>(hG, als, ald, offs, csr, b0, lng0,
                                      lnb0, hbf1, rw0, hbf0);

  // ---- layer 1 (residual = identity on hbf0)
  gemm_mfma_bf_al<<<g256, 256, 0, stream>>>(hbf0, W1T, hG, as1, ad1, als, ald, NN, 256);
  agg_epi_w<<<gagg, 256, 0, stream>>>(hG, als, ald, offs, csr, b1, lng1,
                                      lnb1, hbf0, rw1, hbf1);   // hbf1 = hB

  // ---- layer 2
  if (full && res2) {
    gemm_l2a<<<dim3(3, (NN + 63) / 64), 256, 0, stream>>>(hbf1, V16, rW2T, rb2,
                                                          als, ald, res2, NN);
    agg_y_w<<<gagg, 256, 0, stream>>>(hbf1, als, ald, offs, csr, Ybuf);
    float* partial = bufH;   // bufH+bufR contiguous, dead here
    gemm_y_tiled<<<dim3((NN + 63) / 64, 4), 256, 0, stream>>>(Ybuf, WstkT,
                                                              partial, NN);
    epi_out_res4<<<NN, 128, 0, stream>>>(partial, b2, lng2, lnb2, res2, rw2, outp);
  } else if (full) {
    gemm_al16<<<(NN + 63) / 64, 256, 0, stream>>>(hbf1, V16, als, ald, NN);
    agg_y_w<<<gagg, 256, 0, stream>>>(hbf1, als, ald, offs, csr, Ybuf);
    gemm_mfma<<<g128, 256, 0, stream>>>(Ybuf, WstkT, nullptr, outp, NN, 2048, 128);
    epi_out_mv<<<NN, 128, 0, stream>>>(outp, b2, lng2, lnb2, hbf1, rW2, rb2, rw2);
  } else {
    if (res2)
      gemm_mfma<<<g128, 256, 0, stream>>>(hbf1, rW2T, rb2, res2, NN, 256, 128);
    zero_f32<<<(NN * 128 + 255) / 256, 256, 0, stream>>>(outp, NN * 128);
    for (int p = 0; p < 4; ++p) {
      gemm_mfma<<<g256, 256, 0, stream>>>(hbf1, W2T + (size_t)p * 256 * 256, nullptr,
                                          bufH, NN, 256, 256);
      al2<<<NN, 256, 0, stream>>>(bufH, as2 + p * 256, ad2 + p * 256, als, ald);
      agg2_pair<<<NN, 256, 0, stream>>>(bufH, als, ald, offs, csr, outp);
    }
    if (res2)
      epi_out_res<<<NN, 128, 0, stream>>>(outp, b2, lng2, lnb2, res2, rw2);
    else
      epi_out_mv<<<NN, 128, 0, stream>>>(outp, b2, lng2, lnb2, hbf1, rW2, rb2, rw2);
  }
}